// Round 2
// baseline (302.541 us; speedup 1.0000x reference)
//
#include <hip/hip_runtime.h>
#include <hip/hip_bf16.h>
#include <math.h>

typedef unsigned short u16;
typedef unsigned int   u32;
typedef __attribute__((ext_vector_type(8))) short bf16x8;
typedef __attribute__((ext_vector_type(4))) float f32x4;
typedef __attribute__((ext_vector_type(4))) unsigned short u16x4;
typedef __attribute__((ext_vector_type(4))) unsigned int   u32x4;

#define T_SEQ 2048
#define BATCH 2
#define NHEAD 16
#define KVHEADS 4
#define HD 128
#define DM 2048
#define QKV_N 3072
#define MROWS 4096

__device__ __forceinline__ float bf2f(u16 u) {
    union { u32 i; float f; } v; v.i = ((u32)u) << 16; return v.f;
}
__device__ __forceinline__ u16 f2bf(float f) {
    u32 x = __float_as_uint(f);
    u32 r = (x + 0x7fffu + ((x >> 16) & 1u)) >> 16;
    return (u16)r;
}

// ---------------------------------------------------------------------------
// fp32 -> bf16 elementwise convert (grid-stride, 4 elems/thread/iter)
// ---------------------------------------------------------------------------
__global__ void cvt_f32_bf16(const float* __restrict__ in, u16* __restrict__ out, int nq)
{
    int i = blockIdx.x * blockDim.x + threadIdx.x;
    const int stride = gridDim.x * blockDim.x;
    for (; i < nq; i += stride) {
        f32x4 v = ((const f32x4*)in)[i];
        u16x4 o = { f2bf(v[0]), f2bf(v[1]), f2bf(v[2]), f2bf(v[3]) };
        ((u16x4*)out)[i] = o;
    }
}

// ---------------------------------------------------------------------------
// GEMM: C[M,N] = A[M,K] @ B[N,K]^T + bias  (A,B bf16 LDS tiles, fp32 acc)
// 128x128 tile, BK=64, 256 threads (2x2 waves, each 64x64 = 4x4 frags of 16x16)
// LDS XOR-swizzled (byte ^= (row&7)<<4) so ds_read_b128 is bank-uniform.
// EPI==0: write bf16 to qkv rows (cols<2560) and transposed Vt (cols>=2560)
// EPI==1: write fp32 to Cf with stride DM (final output)
// ---------------------------------------------------------------------------
template <int EPI>
__global__ __launch_bounds__(256, 2)
void gemm_bt(const u16* __restrict__ A, const u16* __restrict__ Bw,
             const float* __restrict__ bias, u16* __restrict__ C,
             float* __restrict__ Cf, u16* __restrict__ Vt, int M, int N, int K)
{
    __shared__ __align__(16) u16 As[128 * 64];
    __shared__ __align__(16) u16 Bs[128 * 64];

    const int tid = threadIdx.x;
    const int l = tid & 63;
    const int w = tid >> 6;
    const int wr = w >> 1, wc = w & 1;
    const int bm = blockIdx.x, bn = blockIdx.y;

    // staging map: thread covers rows rb+32j (j=0..3), 16B slot sb
    const int rb = tid >> 3;
    const int sb = tid & 7;
    const size_t aG0 = (size_t)(bm * 128 + rb) * K + sb * 8;
    const size_t bG0 = (size_t)(bn * 128 + rb) * K + sb * 8;
    const int wOff = rb * 128 + ((sb * 16) ^ ((rb & 7) << 4));

    // fragment read offsets (bytes), kk toggled via ^(kk<<6)
    const int sw = (l & 7) << 4;
    int offA[4], offB[4];
#pragma unroll
    for (int mf = 0; mf < 4; ++mf)
        offA[mf] = (wr * 64 + mf * 16 + (l & 15)) * 128 + (((l >> 4) * 16) ^ sw);
#pragma unroll
    for (int nf = 0; nf < 4; ++nf)
        offB[nf] = (wc * 64 + nf * 16 + (l & 15)) * 128 + (((l >> 4) * 16) ^ sw);

    f32x4 acc[4][4];
#pragma unroll
    for (int i = 0; i < 4; ++i)
#pragma unroll
        for (int j = 0; j < 4; ++j)
            acc[i][j] = (f32x4){0.f, 0.f, 0.f, 0.f};

    const int nK = K >> 6;
    u32x4 pa[4], pb[4];
#pragma unroll
    for (int j = 0; j < 4; ++j) {
        pa[j] = *(const u32x4*)(A + aG0 + (size_t)j * 32 * K);
        pb[j] = *(const u32x4*)(Bw + bG0 + (size_t)j * 32 * K);
    }

    for (int kt = 0; kt < nK; ++kt) {
#pragma unroll
        for (int j = 0; j < 4; ++j) {
            *(u32x4*)((char*)As + wOff + j * 4096) = pa[j];
            *(u32x4*)((char*)Bs + wOff + j * 4096) = pb[j];
        }
        __syncthreads();
        if (kt + 1 < nK) {
#pragma unroll
            for (int j = 0; j < 4; ++j) {
                pa[j] = *(const u32x4*)(A + aG0 + (size_t)(kt + 1) * 64 + (size_t)j * 32 * K);
                pb[j] = *(const u32x4*)(Bw + bG0 + (size_t)(kt + 1) * 64 + (size_t)j * 32 * K);
            }
        }
#pragma unroll
        for (int kk = 0; kk < 2; ++kk) {
            bf16x8 af[4], bfr[4];
#pragma unroll
            for (int mf = 0; mf < 4; ++mf)
                af[mf] = *(const bf16x8*)((const char*)As + (offA[mf] ^ (kk << 6)));
#pragma unroll
            for (int nf = 0; nf < 4; ++nf)
                bfr[nf] = *(const bf16x8*)((const char*)Bs + (offB[nf] ^ (kk << 6)));
#pragma unroll
            for (int mf = 0; mf < 4; ++mf)
#pragma unroll
                for (int nf = 0; nf < 4; ++nf)
                    acc[mf][nf] = __builtin_amdgcn_mfma_f32_16x16x32_bf16(
                        af[mf], bfr[nf], acc[mf][nf], 0, 0, 0);
        }
        __syncthreads();
    }

    // epilogue: C/D layout col=l&15, row=(l>>4)*4+i
    const int row0 = bm * 128 + wr * 64 + ((l >> 4) << 2);
    const int col0 = bn * 128 + wc * 64 + (l & 15);
#pragma unroll
    for (int mf = 0; mf < 4; ++mf) {
#pragma unroll
        for (int nf = 0; nf < 4; ++nf) {
            const int row = row0 + mf * 16;
            const int col = col0 + nf * 16;
            const float bv = bias[col];
            float v0 = acc[mf][nf][0] + bv;
            float v1 = acc[mf][nf][1] + bv;
            float v2 = acc[mf][nf][2] + bv;
            float v3 = acc[mf][nf][3] + bv;
            if (EPI == 0) {
                if (col < 2560) {  // Q + K region -> row-major qkv (bf16)
                    C[(size_t)(row + 0) * QKV_N + col] = f2bf(v0);
                    C[(size_t)(row + 1) * QKV_N + col] = f2bf(v1);
                    C[(size_t)(row + 2) * QKV_N + col] = f2bf(v2);
                    C[(size_t)(row + 3) * QKV_N + col] = f2bf(v3);
                } else {           // V region -> transposed Vt[b][kvh][d][t] (bf16)
                    const int dd = col - 2560;
                    const int kv = dd >> 7;
                    const int d = dd & 127;
                    const int bidx = row >> 11;
                    const int tt = row & 2047;  // multiple of 4
                    u16x4 pv = {f2bf(v0), f2bf(v1), f2bf(v2), f2bf(v3)};
                    *(u16x4*)(Vt + ((size_t)((bidx * KVHEADS + kv) * HD + d)) * T_SEQ + tt) = pv;
                }
            } else {               // final output: fp32
                Cf[(size_t)(row + 0) * DM + col] = v0;
                Cf[(size_t)(row + 1) * DM + col] = v1;
                Cf[(size_t)(row + 2) * DM + col] = v2;
                Cf[(size_t)(row + 3) * DM + col] = v3;
            }
        }
    }
}

// ---------------------------------------------------------------------------
// Flash attention w/ analytic ALiBi + causal mask.
// Block: 64 q-rows, 4 waves x 16 rows. KV tiles of 64. 16x16x32 bf16 MFMA.
// Q/K tiles [64][128] swizzled; V tile [128][64] (d-major, from Vt) swizzled;
// P (16x64 per wave) through per-wave LDS, swizzled.
// ---------------------------------------------------------------------------
__global__ __launch_bounds__(256, 2)
void attn_fwd(const u16* __restrict__ qkv, const u16* __restrict__ Vt,
              u16* __restrict__ AO)
{
    __shared__ __align__(16) u16 Qs[64 * 128];
    __shared__ __align__(16) u16 Ks[64 * 128];
    __shared__ __align__(16) u16 Vs[128 * 64];
    __shared__ __align__(16) u16 Ps[4 * 16 * 64];

    const int tid = threadIdx.x;
    const int l = tid & 63;
    const int w = tid >> 6;
    const int b = blockIdx.y >> 4;
    const int h = blockIdx.y & 15;
    const int kvh = h >> 2;
    const int q0 = blockIdx.x << 6;

    // ---- stage Q (once) ----
    {
        const int rq = tid >> 4, sq = tid & 15;
        const size_t g = (size_t)(b * T_SEQ + q0 + rq) * QKV_N + h * HD + sq * 8;
        const int lo = rq * 256 + ((sq * 16) ^ ((rq & 7) << 4));
#pragma unroll
        for (int j = 0; j < 4; ++j)
            *(u32x4*)((char*)Qs + lo + j * 16 * 256) =
                *(const u32x4*)(qkv + g + (size_t)j * 16 * QKV_N);
    }

    const int sw = (l & 7) << 4;
    const int offQ0 = (w * 16 + (l & 15)) * 256 + (((l >> 4) * 16) ^ sw);
    int offK0[4];
#pragma unroll
    for (int nf = 0; nf < 4; ++nf)
        offK0[nf] = (nf * 16 + (l & 15)) * 256 + (((l >> 4) * 16) ^ sw);

    // staging maps for K and V tiles
    const int rk = tid >> 4, skk = tid & 15;
    const int loK = rk * 256 + ((skk * 16) ^ ((rk & 7) << 4));
    const size_t gK0 = (size_t)(b * T_SEQ + rk) * QKV_N + 2048 + kvh * HD + skk * 8;
    const int rv = tid >> 3, svv = tid & 7;
    const int loV = rv * 128 + ((svv * 16) ^ ((rv & 7) << 4));
    const size_t gV0 = (size_t)((b * KVHEADS + kvh) * HD + rv) * T_SEQ + svv * 8;

    // ALiBi: slope = 2^(-8*(h+1)/16) = 2^(-(h+1)/2); bias = slope*(s-t)
    const float slope = exp2f(-0.5f * (float)(h + 1));
    const int tb = q0 + w * 16 + ((l >> 4) << 2);  // this lane's first q row (+i)
    const float scale = 0.08838834764831845f;      // 1/sqrt(128)

    float m_run[4], l_run[4];
    f32x4 o[8];
#pragma unroll
    for (int i = 0; i < 4; ++i) { m_run[i] = -__builtin_inff(); l_run[i] = 0.f; }
#pragma unroll
    for (int nf = 0; nf < 8; ++nf) o[nf] = (f32x4){0.f, 0.f, 0.f, 0.f};

    const int ntiles = (q0 >> 6) + 1;
    for (int jt = 0; jt < ntiles; ++jt) {
        const int s0 = jt << 6;
        if (jt) __syncthreads();  // prior tile's reads done before overwrite
        // ---- stage K tile [64 s][128 d] ----
#pragma unroll
        for (int j = 0; j < 4; ++j)
            *(u32x4*)((char*)Ks + loK + j * 16 * 256) =
                *(const u32x4*)(qkv + gK0 + (size_t)(s0 + j * 16) * QKV_N);
        // ---- stage V tile [128 d][64 s] from Vt ----
#pragma unroll
        for (int j = 0; j < 4; ++j)
            *(u32x4*)((char*)Vs + loV + j * 32 * 128) =
                *(const u32x4*)(Vt + gV0 + s0 + (size_t)j * 32 * T_SEQ);
        __syncthreads();

        // ---- S = Q K^T (wave's 16 rows x 64 cols) ----
        f32x4 sc[4];
#pragma unroll
        for (int nf = 0; nf < 4; ++nf) sc[nf] = (f32x4){0.f, 0.f, 0.f, 0.f};
#pragma unroll
        for (int kk = 0; kk < 4; ++kk) {
            bf16x8 qa = *(const bf16x8*)((const char*)Qs + (offQ0 ^ (kk << 6)));
#pragma unroll
            for (int nf = 0; nf < 4; ++nf) {
                bf16x8 kb = *(const bf16x8*)((const char*)Ks + (offK0[nf] ^ (kk << 6)));
                sc[nf] = __builtin_amdgcn_mfma_f32_16x16x32_bf16(qa, kb, sc[nf], 0, 0, 0);
            }
        }

        // ---- scale + analytic alibi + causal mask ----
        float vals[4][4];
#pragma unroll
        for (int nf = 0; nf < 4; ++nf) {
            const int scol = s0 + nf * 16 + (l & 15);
#pragma unroll
            for (int i = 0; i < 4; ++i) {
                const int trow = tb + i;
                const float bias = slope * (float)(scol - trow);
                const float xv = sc[nf][i] * scale + bias;
                vals[nf][i] = (scol <= trow) ? xv : -__builtin_inff();
            }
        }

        // ---- online softmax (rows live in 16-lane groups) ----
        float tm[4];
#pragma unroll
        for (int i = 0; i < 4; ++i) {
            float mx = fmaxf(fmaxf(vals[0][i], vals[1][i]), fmaxf(vals[2][i], vals[3][i]));
#pragma unroll
            for (int d = 1; d < 16; d <<= 1) mx = fmaxf(mx, __shfl_xor(mx, d, 64));
            tm[i] = mx;
        }
        float corr[4];
#pragma unroll
        for (int i = 0; i < 4; ++i) {
            const float mn = fmaxf(m_run[i], tm[i]);
            corr[i] = __expf(m_run[i] - mn);
            m_run[i] = mn;
        }
        float ps[4] = {0.f, 0.f, 0.f, 0.f};
#pragma unroll
        for (int nf = 0; nf < 4; ++nf)
#pragma unroll
            for (int i = 0; i < 4; ++i) {
                const float p = __expf(vals[nf][i] - m_run[i]);
                vals[nf][i] = p;
                ps[i] += p;
            }
#pragma unroll
        for (int i = 0; i < 4; ++i) {
#pragma unroll
            for (int d = 1; d < 16; d <<= 1) ps[i] += __shfl_xor(ps[i], d, 64);
            l_run[i] = l_run[i] * corr[i] + ps[i];
        }
#pragma unroll
        for (int nf = 0; nf < 8; ++nf) {
            o[nf][0] *= corr[0]; o[nf][1] *= corr[1];
            o[nf][2] *= corr[2]; o[nf][3] *= corr[3];
        }

        // ---- P -> per-wave LDS (bf16, swizzled) ----
        const int pbase = w * 2048;
#pragma unroll
        for (int nf = 0; nf < 4; ++nf)
#pragma unroll
            for (int i = 0; i < 4; ++i) {
                const int r = ((l >> 4) << 2) + i;
                const int off = pbase + ((r * 128 + nf * 32 + ((l & 15) << 1)) ^ ((r & 7) << 4));
                *(u16*)((char*)Ps + off) = f2bf(vals[nf][i]);
            }

        // ---- O += P @ V ----
        const int rp = l & 15;
#pragma unroll
        for (int kk = 0; kk < 2; ++kk) {
            bf16x8 pfr = *(const bf16x8*)((const char*)Ps + pbase +
                          (rp * 128 + ((((l >> 4) * 16) ^ sw) ^ (kk << 6))));
#pragma unroll
            for (int nf = 0; nf < 8; ++nf) {
                const int offv = (nf * 16 + (l & 15)) * 128 + ((((l >> 4) * 16) ^ sw) ^ (kk << 6));
                bf16x8 vb = *(const bf16x8*)((const char*)Vs + offv);
                o[nf] = __builtin_amdgcn_mfma_f32_16x16x32_bf16(pfr, vb, o[nf], 0, 0, 0);
            }
        }
    }

    // ---- epilogue: O / l -> attn_out [4096][2048] bf16 ----
    float rinv[4];
#pragma unroll
    for (int i = 0; i < 4; ++i) rinv[i] = 1.f / l_run[i];
    const size_t orow = (size_t)(b * T_SEQ + q0 + w * 16 + ((l >> 4) << 2));
#pragma unroll
    for (int nf = 0; nf < 8; ++nf) {
        const int col = h * HD + nf * 16 + (l & 15);
#pragma unroll
        for (int i = 0; i < 4; ++i)
            AO[(orow + i) * DM + col] = f2bf(o[nf][i] * rinv[i]);
    }
}

// ---------------------------------------------------------------------------
extern "C" void kernel_launch(void* const* d_in, const int* in_sizes, int n_in,
                              void* d_out, int out_size, void* d_ws, size_t ws_size,
                              hipStream_t stream)
{
    const float* x      = (const float*)d_in[0];
    // d_in[1] = attn_mask (causal tril, computed analytically)
    // d_in[2] = alibi_bias (computed analytically)
    const float* qkv_w  = (const float*)d_in[3];
    const float* qkv_b  = (const float*)d_in[4];
    const float* proj_w = (const float*)d_in[5];
    const float* proj_b = (const float*)d_in[6];
    float* out = (float*)d_out;

    // ws layout (bf16 elems): xb (aliased by AO after gemm0) | qwb | pwb | qkv | Vt
    u16* ws  = (u16*)d_ws;
    u16* xb  = ws;                                   // 4096*2048   = 8388608
    u16* AO  = ws;                                   // alias: x dead after gemm0
    u16* qwb = ws + 8388608;                         // 3072*2048   = 6291456
    u16* pwb = qwb + 6291456;                        // 2048*2048   = 4194304
    u16* qkv = pwb + 4194304;                        // 4096*3072   = 12582912
    u16* Vt  = qkv + 12582912;                       // 2*4*128*2048= 2097152
    // total: 33554432 elems = 64 MiB

    cvt_f32_bf16<<<2048, 256, 0, stream>>>(x,      xb,  8388608 / 4);
    cvt_f32_bf16<<<2048, 256, 0, stream>>>(qkv_w,  qwb, 6291456 / 4);
    cvt_f32_bf16<<<1024, 256, 0, stream>>>(proj_w, pwb, 4194304 / 4);

    gemm_bt<0><<<dim3(32, 24), 256, 0, stream>>>(xb, qwb, qkv_b, qkv, nullptr, Vt,
                                                 MROWS, QKV_N, DM);
    attn_fwd<<<dim3(32, 32), 256, 0, stream>>>(qkv, Vt, AO);
    gemm_bt<1><<<dim3(32, 16), 256, 0, stream>>>(AO, pwb, proj_b, nullptr, out, nullptr,
                                                 MROWS, DM, DM);
}

// Round 3
// 214.743 us; speedup vs baseline: 1.4088x; 1.4088x over previous
//
#include <hip/hip_runtime.h>
#include <hip/hip_bf16.h>
#include <math.h>

typedef unsigned short u16;
typedef unsigned int   u32;
typedef __attribute__((ext_vector_type(8))) short bf16x8;
typedef __attribute__((ext_vector_type(4))) float f32x4;
typedef __attribute__((ext_vector_type(4))) unsigned short u16x4;
typedef __attribute__((ext_vector_type(4))) unsigned int   u32x4;

#define T_SEQ 2048
#define BATCH 2
#define NHEAD 16
#define KVHEADS 4
#define HD 128
#define DM 2048
#define QKV_N 3072
#define MROWS 4096

__device__ __forceinline__ float bf2f(u16 u) {
    union { u32 i; float f; } v; v.i = ((u32)u) << 16; return v.f;
}
__device__ __forceinline__ u16 f2bf(float f) {
    u32 x = __float_as_uint(f);
    u32 r = (x + 0x7fffu + ((x >> 16) & 1u)) >> 16;
    return (u16)r;
}

// ---------------------------------------------------------------------------
// fp32 -> bf16 elementwise convert (grid-stride, 4 elems/thread/iter)
// ---------------------------------------------------------------------------
__global__ void cvt_f32_bf16(const float* __restrict__ in, u16* __restrict__ out, int nq)
{
    int i = blockIdx.x * blockDim.x + threadIdx.x;
    const int stride = gridDim.x * blockDim.x;
    for (; i < nq; i += stride) {
        f32x4 v = ((const f32x4*)in)[i];
        u16x4 o = { f2bf(v[0]), f2bf(v[1]), f2bf(v[2]), f2bf(v[3]) };
        ((u16x4*)out)[i] = o;
    }
}

// ---------------------------------------------------------------------------
// GEMM: C[M,N] = A[M,K] @ B[N,K]^T + bias  (A,B bf16 LDS tiles, fp32 acc)
// 128x128 tile, BK=64, 256 threads (2x2 waves, each 64x64 = 4x4 frags of 16x16)
// LDS XOR-swizzled (byte ^= (row&7)<<4) so ds_read_b128 is bank-uniform.
// EPI==0: write bf16 to qkv rows (cols<2560) and transposed Vt (cols>=2560)
// EPI==1: write fp32 to Cf with stride DM (final output)
// ---------------------------------------------------------------------------
template <int EPI>
__global__ __launch_bounds__(256, 2)
void gemm_bt(const u16* __restrict__ A, const u16* __restrict__ Bw,
             const float* __restrict__ bias, u16* __restrict__ C,
             float* __restrict__ Cf, u16* __restrict__ Vt, int M, int N, int K)
{
    __shared__ __align__(16) u16 As[128 * 64];
    __shared__ __align__(16) u16 Bs[128 * 64];

    const int tid = threadIdx.x;
    const int l = tid & 63;
    const int w = tid >> 6;
    const int wr = w >> 1, wc = w & 1;
    const int bm = blockIdx.x, bn = blockIdx.y;

    // staging map: thread covers rows rb+32j (j=0..3), 16B slot sb
    const int rb = tid >> 3;
    const int sb = tid & 7;
    const size_t aG0 = (size_t)(bm * 128 + rb) * K + sb * 8;
    const size_t bG0 = (size_t)(bn * 128 + rb) * K + sb * 8;
    const int wOff = rb * 128 + ((sb * 16) ^ ((rb & 7) << 4));

    // fragment read offsets (bytes), kk toggled via ^(kk<<6)
    const int sw = (l & 7) << 4;
    int offA[4], offB[4];
#pragma unroll
    for (int mf = 0; mf < 4; ++mf)
        offA[mf] = (wr * 64 + mf * 16 + (l & 15)) * 128 + (((l >> 4) * 16) ^ sw);
#pragma unroll
    for (int nf = 0; nf < 4; ++nf)
        offB[nf] = (wc * 64 + nf * 16 + (l & 15)) * 128 + (((l >> 4) * 16) ^ sw);

    f32x4 acc[4][4];
#pragma unroll
    for (int i = 0; i < 4; ++i)
#pragma unroll
        for (int j = 0; j < 4; ++j)
            acc[i][j] = (f32x4){0.f, 0.f, 0.f, 0.f};

    const int nK = K >> 6;
    u32x4 pa[4], pb[4];
#pragma unroll
    for (int j = 0; j < 4; ++j) {
        pa[j] = *(const u32x4*)(A + aG0 + (size_t)j * 32 * K);
        pb[j] = *(const u32x4*)(Bw + bG0 + (size_t)j * 32 * K);
    }

    for (int kt = 0; kt < nK; ++kt) {
#pragma unroll
        for (int j = 0; j < 4; ++j) {
            *(u32x4*)((char*)As + wOff + j * 4096) = pa[j];
            *(u32x4*)((char*)Bs + wOff + j * 4096) = pb[j];
        }
        __syncthreads();
        if (kt + 1 < nK) {
#pragma unroll
            for (int j = 0; j < 4; ++j) {
                pa[j] = *(const u32x4*)(A + aG0 + (size_t)(kt + 1) * 64 + (size_t)j * 32 * K);
                pb[j] = *(const u32x4*)(Bw + bG0 + (size_t)(kt + 1) * 64 + (size_t)j * 32 * K);
            }
        }
#pragma unroll
        for (int kk = 0; kk < 2; ++kk) {
            bf16x8 af[4], bfr[4];
#pragma unroll
            for (int mf = 0; mf < 4; ++mf)
                af[mf] = *(const bf16x8*)((const char*)As + (offA[mf] ^ (kk << 6)));
#pragma unroll
            for (int nf = 0; nf < 4; ++nf)
                bfr[nf] = *(const bf16x8*)((const char*)Bs + (offB[nf] ^ (kk << 6)));
            __builtin_amdgcn_s_setprio(1);
#pragma unroll
            for (int mf = 0; mf < 4; ++mf)
#pragma unroll
                for (int nf = 0; nf < 4; ++nf)
                    acc[mf][nf] = __builtin_amdgcn_mfma_f32_16x16x32_bf16(
                        af[mf], bfr[nf], acc[mf][nf], 0, 0, 0);
            __builtin_amdgcn_s_setprio(0);
        }
        __syncthreads();
    }

    // epilogue: C/D layout col=l&15, row=(l>>4)*4+i
    const int row0 = bm * 128 + wr * 64 + ((l >> 4) << 2);
    const int col0 = bn * 128 + wc * 64 + (l & 15);
#pragma unroll
    for (int mf = 0; mf < 4; ++mf) {
#pragma unroll
        for (int nf = 0; nf < 4; ++nf) {
            const int row = row0 + mf * 16;
            const int col = col0 + nf * 16;
            const float bv = bias[col];
            float v0 = acc[mf][nf][0] + bv;
            float v1 = acc[mf][nf][1] + bv;
            float v2 = acc[mf][nf][2] + bv;
            float v3 = acc[mf][nf][3] + bv;
            if (EPI == 0) {
                if (col < 2560) {  // Q + K region -> row-major qkv (bf16)
                    C[(size_t)(row + 0) * QKV_N + col] = f2bf(v0);
                    C[(size_t)(row + 1) * QKV_N + col] = f2bf(v1);
                    C[(size_t)(row + 2) * QKV_N + col] = f2bf(v2);
                    C[(size_t)(row + 3) * QKV_N + col] = f2bf(v3);
                } else {           // V region -> transposed Vt[b][kvh][d][t] (bf16)
                    const int dd = col - 2560;
                    const int kv = dd >> 7;
                    const int d = dd & 127;
                    const int bidx = row >> 11;
                    const int tt = row & 2047;  // multiple of 4
                    u16x4 pv = {f2bf(v0), f2bf(v1), f2bf(v2), f2bf(v3)};
                    *(u16x4*)(Vt + ((size_t)((bidx * KVHEADS + kv) * HD + d)) * T_SEQ + tt) = pv;
                }
            } else {               // final output: fp32
                Cf[(size_t)(row + 0) * DM + col] = v0;
                Cf[(size_t)(row + 1) * DM + col] = v1;
                Cf[(size_t)(row + 2) * DM + col] = v2;
                Cf[(size_t)(row + 3) * DM + col] = v3;
            }
        }
    }
}

// ---------------------------------------------------------------------------
// Flash attention w/ analytic ALiBi + causal mask.
// Grid (16, B*H): block px handles q-tiles {px, 31-px} sequentially -> every
// block does exactly 33 KV-tile iterations (causal load balance).
// 4 waves x 16 q-rows, KV tiles of 64, 16x16x32 bf16 MFMA.
// Q in registers; K/V register-prefetched (T14) into single-buffered LDS;
// P (16x64 per wave) through per-wave LDS. All LDS XOR-swizzled.
// ---------------------------------------------------------------------------
__global__ __launch_bounds__(256, 3)
void attn_fwd(const u16* __restrict__ qkv, const u16* __restrict__ Vt,
              u16* __restrict__ AO)
{
    __shared__ __align__(16) u16 Ks[64 * 128];
    __shared__ __align__(16) u16 Vs[128 * 64];
    __shared__ __align__(16) u16 Ps[4 * 16 * 64];

    const int tid = threadIdx.x;
    const int l = tid & 63;
    const int w = tid >> 6;
    const int b = blockIdx.y >> 4;
    const int h = blockIdx.y & 15;
    const int kvh = h >> 2;
    const int px = blockIdx.x;          // 0..15

    const int sw = (l & 7) << 4;
    int offK0[4];
#pragma unroll
    for (int nf = 0; nf < 4; ++nf)
        offK0[nf] = (nf * 16 + (l & 15)) * 256 + (((l >> 4) * 16) ^ sw);

    // staging maps for K and V tiles
    const int rk = tid >> 4, skk = tid & 15;
    const int loK = rk * 256 + ((skk * 16) ^ ((rk & 7) << 4));
    const size_t gK0 = (size_t)(b * T_SEQ + rk) * QKV_N + 2048 + kvh * HD + skk * 8;
    const int rv = tid >> 3, svv = tid & 7;
    const int loV = rv * 128 + ((svv * 16) ^ ((rv & 7) << 4));
    const size_t gV0 = (size_t)((b * KVHEADS + kvh) * HD + rv) * T_SEQ + svv * 8;

    // ALiBi: slope = 2^(-8*(h+1)/16) = 2^(-(h+1)/2); bias = slope*(s-t)
    const float slope = exp2f(-0.5f * (float)(h + 1));
    const float scale = 0.08838834764831845f;      // 1/sqrt(128)

    const int n0 = px + 1;              // tiles for q-tile px
    const int total = 33;               // n0 + (32 - px)

    int qt = px;
    int q0 = qt << 6;

    // Q fragments in registers: frag kk = Q[q0 + w*16 + (l&15)][kk*32 + (l>>4)*8 ..]
    const size_t qrow_off = (size_t)h * HD + ((l >> 4) << 3);
    bf16x8 qreg[4];
#pragma unroll
    for (int kk = 0; kk < 4; ++kk)
        qreg[kk] = *(const bf16x8*)(qkv +
            (size_t)(b * T_SEQ + q0 + w * 16 + (l & 15)) * QKV_N + qrow_off + kk * 32);

    float m_run[4], l_run[4];
    f32x4 o[8];
#pragma unroll
    for (int i = 0; i < 4; ++i) { m_run[i] = -__builtin_inff(); l_run[i] = 0.f; }
#pragma unroll
    for (int nf = 0; nf < 8; ++nf) o[nf] = (f32x4){0.f, 0.f, 0.f, 0.f};

    // prefetch tile 0 into registers
    u32x4 pk[4], pv[4];
#pragma unroll
    for (int j = 0; j < 4; ++j) {
        pk[j] = *(const u32x4*)(qkv + gK0 + (size_t)(j * 16) * QKV_N);
        pv[j] = *(const u32x4*)(Vt + gV0 + (size_t)j * 32 * T_SEQ);
    }

    for (int it = 0; it < total; ++it) {
        if (it == n0) {
            // ---- epilogue for q-tile qt, then switch to q-tile 31-px ----
            float rinv[4];
#pragma unroll
            for (int i = 0; i < 4; ++i) rinv[i] = 1.f / l_run[i];
            const size_t orow = (size_t)(b * T_SEQ + q0 + w * 16 + ((l >> 4) << 2));
#pragma unroll
            for (int nf = 0; nf < 8; ++nf) {
                const int col = h * HD + nf * 16 + (l & 15);
#pragma unroll
                for (int i = 0; i < 4; ++i)
                    AO[(orow + i) * DM + col] = f2bf(o[nf][i] * rinv[i]);
            }
            qt = 31 - px;
            q0 = qt << 6;
#pragma unroll
            for (int kk = 0; kk < 4; ++kk)
                qreg[kk] = *(const bf16x8*)(qkv +
                    (size_t)(b * T_SEQ + q0 + w * 16 + (l & 15)) * QKV_N + qrow_off + kk * 32);
#pragma unroll
            for (int i = 0; i < 4; ++i) { m_run[i] = -__builtin_inff(); l_run[i] = 0.f; }
#pragma unroll
            for (int nf = 0; nf < 8; ++nf) o[nf] = (f32x4){0.f, 0.f, 0.f, 0.f};
        }
        const int jt = (it < n0) ? it : it - n0;
        const int s0 = jt << 6;
        const bool diag = (jt == qt);
        const int tb = q0 + w * 16 + ((l >> 4) << 2);

        // ---- publish prefetched K/V tile to LDS ----
        __syncthreads();   // prior tile's reads complete
#pragma unroll
        for (int j = 0; j < 4; ++j) {
            *(u32x4*)((char*)Ks + loK + j * 16 * 256) = pk[j];
            *(u32x4*)((char*)Vs + loV + j * 32 * 128) = pv[j];
        }
        __syncthreads();

        // ---- prefetch next tile into registers (hidden under compute) ----
        const int nit = it + 1;
        if (nit < total) {
            const int ns0 = (nit == n0) ? 0 : (((nit < n0) ? nit : nit - n0) << 6);
#pragma unroll
            for (int j = 0; j < 4; ++j) {
                pk[j] = *(const u32x4*)(qkv + gK0 + (size_t)(ns0 + j * 16) * QKV_N);
                pv[j] = *(const u32x4*)(Vt + gV0 + ns0 + (size_t)j * 32 * T_SEQ);
            }
        }

        // ---- S = Q K^T (wave's 16 rows x 64 cols) ----
        f32x4 sc[4];
#pragma unroll
        for (int nf = 0; nf < 4; ++nf) sc[nf] = (f32x4){0.f, 0.f, 0.f, 0.f};
        __builtin_amdgcn_s_setprio(1);
#pragma unroll
        for (int kk = 0; kk < 4; ++kk) {
#pragma unroll
            for (int nf = 0; nf < 4; ++nf) {
                bf16x8 kb = *(const bf16x8*)((const char*)Ks + (offK0[nf] ^ (kk << 6)));
                sc[nf] = __builtin_amdgcn_mfma_f32_16x16x32_bf16(qreg[kk], kb, sc[nf], 0, 0, 0);
            }
        }
        __builtin_amdgcn_s_setprio(0);

        // ---- scale + analytic alibi (+ causal mask only on diagonal tile) ----
        float vals[4][4];
#pragma unroll
        for (int nf = 0; nf < 4; ++nf) {
            const int scol = s0 + nf * 16 + (l & 15);
#pragma unroll
            for (int i = 0; i < 4; ++i) {
                const int trow = tb + i;
                const float bias = slope * (float)(scol - trow);
                const float xv = sc[nf][i] * scale + bias;
                vals[nf][i] = (diag && scol > trow) ? -__builtin_inff() : xv;
            }
        }

        // ---- online softmax (rows live in 16-lane groups) ----
        float tm[4];
#pragma unroll
        for (int i = 0; i < 4; ++i) {
            float mx = fmaxf(fmaxf(vals[0][i], vals[1][i]), fmaxf(vals[2][i], vals[3][i]));
#pragma unroll
            for (int d = 1; d < 16; d <<= 1) mx = fmaxf(mx, __shfl_xor(mx, d, 64));
            tm[i] = mx;
        }
        float corr[4];
#pragma unroll
        for (int i = 0; i < 4; ++i) {
            const float mn = fmaxf(m_run[i], tm[i]);
            corr[i] = __expf(m_run[i] - mn);
            m_run[i] = mn;
        }
        float ps[4] = {0.f, 0.f, 0.f, 0.f};
#pragma unroll
        for (int nf = 0; nf < 4; ++nf)
#pragma unroll
            for (int i = 0; i < 4; ++i) {
                const float p = __expf(vals[nf][i] - m_run[i]);
                vals[nf][i] = p;
                ps[i] += p;
            }
#pragma unroll
        for (int i = 0; i < 4; ++i) {
#pragma unroll
            for (int d = 1; d < 16; d <<= 1) ps[i] += __shfl_xor(ps[i], d, 64);
            l_run[i] = l_run[i] * corr[i] + ps[i];
        }
#pragma unroll
        for (int nf = 0; nf < 8; ++nf) {
            o[nf][0] *= corr[0]; o[nf][1] *= corr[1];
            o[nf][2] *= corr[2]; o[nf][3] *= corr[3];
        }

        // ---- P -> per-wave LDS (bf16, swizzled) ----
        const int pbase = w * 2048;
#pragma unroll
        for (int nf = 0; nf < 4; ++nf)
#pragma unroll
            for (int i = 0; i < 4; ++i) {
                const int r = ((l >> 4) << 2) + i;
                const int off = pbase + ((r * 128 + nf * 32 + ((l & 15) << 1)) ^ ((r & 7) << 4));
                *(u16*)((char*)Ps + off) = f2bf(vals[nf][i]);
            }

        // ---- O += P @ V ----
        const int rp = l & 15;
        __builtin_amdgcn_s_setprio(1);
#pragma unroll
        for (int kk = 0; kk < 2; ++kk) {
            bf16x8 pfr = *(const bf16x8*)((const char*)Ps + pbase +
                          (rp * 128 + ((((l >> 4) * 16) ^ sw) ^ (kk << 6))));
#pragma unroll
            for (int nf = 0; nf < 8; ++nf) {
                const int offv = (nf * 16 + (l & 15)) * 128 + ((((l >> 4) * 16) ^ sw) ^ (kk << 6));
                bf16x8 vb = *(const bf16x8*)((const char*)Vs + offv);
                o[nf] = __builtin_amdgcn_mfma_f32_16x16x32_bf16(pfr, vb, o[nf], 0, 0, 0);
            }
        }
        __builtin_amdgcn_s_setprio(0);
    }

    // ---- final epilogue for q-tile 31-px ----
    float rinv[4];
#pragma unroll
    for (int i = 0; i < 4; ++i) rinv[i] = 1.f / l_run[i];
    const size_t orow = (size_t)(b * T_SEQ + q0 + w * 16 + ((l >> 4) << 2));
#pragma unroll
    for (int nf = 0; nf < 8; ++nf) {
        const int col = h * HD + nf * 16 + (l & 15);
#pragma unroll
        for (int i = 0; i < 4; ++i)
            AO[(orow + i) * DM + col] = f2bf(o[nf][i] * rinv[i]);
    }
}

// ---------------------------------------------------------------------------
extern "C" void kernel_launch(void* const* d_in, const int* in_sizes, int n_in,
                              void* d_out, int out_size, void* d_ws, size_t ws_size,
                              hipStream_t stream)
{
    const float* x      = (const float*)d_in[0];
    // d_in[1] = attn_mask (causal tril, computed analytically)
    // d_in[2] = alibi_bias (computed analytically)
    const float* qkv_w  = (const float*)d_in[3];
    const float* qkv_b  = (const float*)d_in[4];
    const float* proj_w = (const float*)d_in[5];
    const float* proj_b = (const float*)d_in[6];
    float* out = (float*)d_out;

    // ws layout (bf16 elems): xb (aliased by AO after gemm0) | qwb | pwb | qkv | Vt
    u16* ws  = (u16*)d_ws;
    u16* xb  = ws;                                   // 4096*2048   = 8388608
    u16* AO  = ws;                                   // alias: x dead after gemm0
    u16* qwb = ws + 8388608;                         // 3072*2048   = 6291456
    u16* pwb = qwb + 6291456;                        // 2048*2048   = 4194304
    u16* qkv = pwb + 4194304;                        // 4096*3072   = 12582912
    u16* Vt  = qkv + 12582912;                       // 2*4*128*2048= 2097152
    // total: 33554432 elems = 64 MiB

    cvt_f32_bf16<<<2048, 256, 0, stream>>>(x,      xb,  8388608 / 4);
    cvt_f32_bf16<<<2048, 256, 0, stream>>>(qkv_w,  qwb, 6291456 / 4);
    cvt_f32_bf16<<<1024, 256, 0, stream>>>(proj_w, pwb, 4194304 / 4);

    gemm_bt<0><<<dim3(32, 24), 256, 0, stream>>>(xb, qwb, qkv_b, qkv, nullptr, Vt,
                                                 MROWS, QKV_N, DM);
    attn_fwd<<<dim3(16, 32), 256, 0, stream>>>(qkv, Vt, AO);
    gemm_bt<1><<<dim3(32, 16), 256, 0, stream>>>(AO, pwb, proj_b, nullptr, out, nullptr,
                                                 MROWS, DM, DM);
}